// Round 2
// 235.677 us; speedup vs baseline: 1.0960x; 1.0960x over previous
//
#include <hip/hip_runtime.h>

#define WINDOW 13
#define NTOT   53248      // 13*64*64 voxels per (b,c)
#define WPB    8          // windows per block
#define VT     104        // real voxels per block (8 windows)
#define VS     112        // staged voxels (7 MFMA col-tiles of 16)
#define WS     72         // bf16 row stride (pad 64->72: bank-quad step 1, conflict-free b128)
#define QKS    112        // qk fp32 row stride
#define VFS    68         // v fp32 row stride (pad 64->68)

typedef float floatx4 __attribute__((ext_vector_type(4)));
typedef short shortx8 __attribute__((ext_vector_type(8)));

__device__ __forceinline__ unsigned short f2bf(float f) {
    union { float f; unsigned int u; } v; v.f = f;
    unsigned int u = v.u;
    unsigned int r = (u + 0x7fffu + ((u >> 16) & 1u)) >> 16;   // RNE
    return (unsigned short)r;
}

__device__ __forceinline__ unsigned int pk2(float a, float b) {
    return (unsigned int)f2bf(a) | ((unsigned int)f2bf(b) << 16);
}

// 512 threads/block, 71 KB LDS -> 2 blocks/CU = 16 waves/CU (was 256 thr -> 8 waves/CU).
__global__ __launch_bounds__(512, 4)
void attn_win13_kernel(const float* __restrict__ x,
                       const float* __restrict__ wq, const float* __restrict__ bq,
                       const float* __restrict__ wk, const float* __restrict__ bk,
                       const float* __restrict__ wv, const float* __restrict__ bv,
                       float* __restrict__ out)
{
    // LDS: 16128 + 11520 + 320 + 30464 + 7168 + 5408 = 71008 B -> 2 blocks/CU
    __shared__ __align__(16) unsigned short xT[VS * WS];   // bf16 x, transposed [vox][ch], padded
    __shared__ __align__(16) unsigned short wbf[80 * WS];  // bf16 weights, rows 0..7 q, 8..15 k, 16..79 v
    __shared__ float ball[80];
    __shared__ __align__(16) float vf[VS * VFS];           // fp32 v, [vox][ch], padded
    __shared__ float qk[16 * QKS];                         // fp32 q rows 0..7, k rows 8..15
    __shared__ float att[WPB * 169];                       // [w][i][j]

    const int tid = threadIdx.x;
    const int b   = blockIdx.y;
    const int v0  = blockIdx.x * VT;
    const size_t total = (size_t)512 * NTOT;   // 8*64 rows of x

    // ---- P1: staging, split across waves.
    // Waves 0..3 (tid<224): x -> bf16 transposed LDS. Each thread owns 8 ch x 4 vox
    // and writes 4 x ds_write_b128 (full 16B row segments). Lane map f = vq*8+cg8:
    //   LDS quad-group = (4vq + r + cg8) % 8 -> uniform 8 lanes/group (wave64-b128 min,
    //   no excess conflicts; old b32 scheme was ~14-way).
    //   Global: per load instr, 8 segments of 8 lanes x 16B = 128B contiguous. ----
    if (tid < 224) {
        const int vq = tid >> 3, cg8 = tid & 7;
        const int c0 = cg8 * 8, vx = vq * 4;
        float xv[4][8];
#pragma unroll
        for (int i = 0; i < 8; ++i) {
            size_t idx = (size_t)(b * 64 + c0 + i) * NTOT + v0 + vx;
            if (idx > total - 4) idx = total - 4;   // clamp tail (garbage MFMA cols)
            const float4 t = *(const float4*)(x + idx);
            xv[0][i] = t.x; xv[1][i] = t.y; xv[2][i] = t.z; xv[3][i] = t.w;
        }
#pragma unroll
        for (int r = 0; r < 4; ++r) {
            uint4 pk;
            pk.x = pk2(xv[r][0], xv[r][1]);
            pk.y = pk2(xv[r][2], xv[r][3]);
            pk.z = pk2(xv[r][4], xv[r][5]);
            pk.w = pk2(xv[r][6], xv[r][7]);
            *(uint4*)(&xT[(vx + r) * WS + c0]) = pk;
        }
    } else if (tid >= 256) {
        // Waves 4..7: weights -> bf16 LDS, b128 writes (8 ch per thread-row-chunk).
        // 640 items (80 rows x 8 col-groups), 2.5 iters over 256 threads.
        const int wf0 = tid - 256;
#pragma unroll
        for (int it = 0; it < 3; ++it) {
            const int wf = wf0 + (it << 8);
            if (wf < 640) {
                const int r = wf >> 3, cw = (wf & 7) * 8;
                const float* src = (r < 8)  ? (wq + r * 64 + cw)
                                 : (r < 16) ? (wk + (r - 8) * 64 + cw)
                                            : (wv + (r - 16) * 64 + cw);
                const float4 w0 = *(const float4*)src;
                const float4 w1 = *(const float4*)(src + 4);
                uint4 pk;
                pk.x = pk2(w0.x, w0.y); pk.y = pk2(w0.z, w0.w);
                pk.z = pk2(w1.x, w1.y); pk.w = pk2(w1.z, w1.w);
                *(uint4*)(&wbf[r * WS + cw]) = pk;
            }
        }
    }
    if (tid >= 432) {   // 80 bias loads on wave 6 upper + wave 7
        const int t2 = tid - 432;
        ball[t2] = (t2 < 8) ? bq[t2] : (t2 < 16) ? bk[t2 - 8] : bv[t2 - 16];
    }
    __syncthreads();

    // ---- P2: projection GEMM via MFMA. 5 m-tiles x 7 n-tiles, K=64 (2 mfma).
    // 35 tiles over 8 waves (max 5/wave; was max 9/wave with 4 waves).
    // A-frag: m=lane&15, k=(lane>>4)*8+j ; B-frag: n=lane&15, same k-chunks;
    // D: row=(lane>>4)*4+reg, col=lane&15  [m89/m91-verified]. ----
    {
        const int wid  = tid >> 6;
        const int lane = tid & 63;
        const int col  = lane & 15;
        const int g    = lane >> 4;          // k-chunk / row-quad
        for (int t = wid; t < 35; t += 8) {
            const int mt = t / 7, nt = t % 7;
            const shortx8 a0 = *(const shortx8*)(&wbf[(mt * 16 + col) * WS + g * 8]);
            const shortx8 b0 = *(const shortx8*)(&xT [(nt * 16 + col) * WS + g * 8]);
            const shortx8 a1 = *(const shortx8*)(&wbf[(mt * 16 + col) * WS + 32 + g * 8]);
            const shortx8 b1 = *(const shortx8*)(&xT [(nt * 16 + col) * WS + 32 + g * 8]);
            floatx4 acc = {0.f, 0.f, 0.f, 0.f};
            acc = __builtin_amdgcn_mfma_f32_16x16x32_bf16(a0, b0, acc, 0, 0, 0);
            acc = __builtin_amdgcn_mfma_f32_16x16x32_bf16(a1, b1, acc, 0, 0, 0);
            const int row0 = mt * 16 + g * 4;
            const int vox  = nt * 16 + col;
            if (mt == 0) {                    // q/k rows -> qk (fp32, row-major)
                qk[(row0 + 0) * QKS + vox] = acc[0] + ball[row0 + 0];
                qk[(row0 + 1) * QKS + vox] = acc[1] + ball[row0 + 1];
                qk[(row0 + 2) * QKS + vox] = acc[2] + ball[row0 + 2];
                qk[(row0 + 3) * QKS + vox] = acc[3] + ball[row0 + 3];
            } else {                          // v rows: 4 consecutive channels -> one b128
                const int c0 = row0 - 16;
                float4 st = make_float4(acc[0] + ball[row0 + 0], acc[1] + ball[row0 + 1],
                                        acc[2] + ball[row0 + 2], acc[3] + ball[row0 + 3]);
                *(float4*)(&vf[vox * VFS + c0]) = st;
            }
        }
    }
    __syncthreads();

    // ---- P3a: scores[w][i][j] = sum_o q[o][w13+i] * k[o][w13+j] ----
    for (int f = tid; f < WPB * 169; f += 512) {
        const int w = f / 169, rem = f % 169;
        const int i = rem / 13, j = rem % 13;
        const float* qp = &qk[w * 13 + i];
        const float* kp = &qk[w * 13 + j];
        float s = 0.f;
#pragma unroll
        for (int o = 0; o < 8; ++o)
            s += qp[o * QKS] * kp[(8 + o) * QKS];
        att[f] = s;
    }
    __syncthreads();

    // ---- P3b: softmax over j (one thread per (w,i) row) ----
    if (tid < WPB * WINDOW) {
        float* row = att + tid * 13;
        float m = row[0];
#pragma unroll
        for (int j = 1; j < 13; ++j) m = fmaxf(m, row[j]);
        float s0 = __expf(row[0] - m), s1 = __expf(row[1] - m), s2 = __expf(row[2] - m);
        float s3 = __expf(row[3] - m), s4 = __expf(row[4] - m), s5 = __expf(row[5] - m);
        float s6 = __expf(row[6] - m), s7 = __expf(row[7] - m), s8 = __expf(row[8] - m);
        float s9 = __expf(row[9] - m), sa = __expf(row[10] - m), sb = __expf(row[11] - m);
        float sc = __expf(row[12] - m);
        const float inv = 1.f / (s0+s1+s2+s3+s4+s5+s6+s7+s8+s9+sa+sb+sc);
        row[0]=s0*inv; row[1]=s1*inv; row[2]=s2*inv; row[3]=s3*inv; row[4]=s4*inv;
        row[5]=s5*inv; row[6]=s6*inv; row[7]=s7*inv; row[8]=s8*inv; row[9]=s9*inv;
        row[10]=sa*inv; row[11]=sb*inv; row[12]=sc*inv;
    }
    __syncthreads();

    // ---- P4: out[4cg+r][vx] = sum_j vf[w13+j][4cg+r] * att[w][i][j].
    // vx-fast mapping -> all 4 global store instrs are voxel-contiguous. ----
    for (int f = tid; f < 16 * VT; f += 512) {
        const int cg = f / VT, vx = f % VT;
        const int w = vx / 13, i = vx % 13;
        const float* arow  = att + w * 169 + i * 13;
        const float* vbase = &vf[(w * 13) * VFS + cg * 4];
        float4 o4 = make_float4(0.f, 0.f, 0.f, 0.f);
#pragma unroll
        for (int j = 0; j < 13; ++j) {
            const float a = arow[j];
            const float4 vv = *(const float4*)(vbase + j * VFS);
            o4.x += a * vv.x; o4.y += a * vv.y; o4.z += a * vv.z; o4.w += a * vv.w;
        }
        float* op = out + (size_t)(b * 64 + cg * 4) * NTOT + v0 + vx;
        op[0]                 = o4.x;
        op[(size_t)NTOT]      = o4.y;
        op[(size_t)2 * NTOT]  = o4.z;
        op[(size_t)3 * NTOT]  = o4.w;
    }
}

extern "C" void kernel_launch(void* const* d_in, const int* in_sizes, int n_in,
                              void* d_out, int out_size, void* d_ws, size_t ws_size,
                              hipStream_t stream) {
    const float* x  = (const float*)d_in[0];
    const float* wq = (const float*)d_in[1];
    const float* bq = (const float*)d_in[2];
    const float* wk = (const float*)d_in[3];
    const float* bk = (const float*)d_in[4];
    const float* wv = (const float*)d_in[5];
    const float* bv = (const float*)d_in[6];
    float* out = (float*)d_out;

    dim3 grid(NTOT / VT, 8);   // 512 tiles x 8 batches = 4096 blocks
    dim3 block(512);
    attn_win13_kernel<<<grid, block, 0, stream>>>(x, wq, bq, wk, bk, wv, bv, out);
}

// Round 3
// 229.934 us; speedup vs baseline: 1.1234x; 1.0250x over previous
//
#include <hip/hip_runtime.h>

#define WINDOW 13
#define NTOT   53248      // 13*64*64 voxels per (b,c)
#define WPB    8          // windows per block
#define VT     104        // real voxels per block (8 windows)
#define VS     112        // staged voxels (7 MFMA col-tiles of 16)
#define WS     72         // bf16 row stride (pad 64->72: bank-quad step 1, conflict-free b128)
#define QKS    112        // qk fp32 row stride

typedef float floatx4 __attribute__((ext_vector_type(4)));
typedef short shortx8 __attribute__((ext_vector_type(8)));

__device__ __forceinline__ unsigned short f2bf(float f) {
    union { float f; unsigned int u; } v; v.f = f;
    unsigned int u = v.u;
    unsigned int r = (u + 0x7fffu + ((u >> 16) & 1u)) >> 16;   // RNE
    return (unsigned short)r;
}

__device__ __forceinline__ unsigned int pk2(float a, float b) {
    return (unsigned int)f2bf(a) | ((unsigned int)f2bf(b) << 16);
}

__device__ __forceinline__ float bflo(unsigned int u) {
    union { unsigned int u; float f; } v; v.u = u << 16; return v.f;
}
__device__ __forceinline__ float bfhi(unsigned int u) {
    union { unsigned int u; float f; } v; v.u = u & 0xffff0000u; return v.f;
}

// 512 threads/block, 50112 B LDS -> 3 blocks/CU = 24 waves/CU (was 71 KB -> 2 blocks -> 16).
__global__ __launch_bounds__(512, 6)
void attn_win13_kernel(const float* __restrict__ x,
                       const float* __restrict__ wq, const float* __restrict__ bq,
                       const float* __restrict__ wk, const float* __restrict__ bk,
                       const float* __restrict__ wv, const float* __restrict__ bv,
                       float* __restrict__ out)
{
    // LDS: 16128 + 11520 + 320 + 14976 + 7168 = 50112 B -> 3 blocks/CU
    __shared__ __align__(16) unsigned short xT[VS * WS];   // bf16 x, transposed [vox][ch], padded
    __shared__ __align__(16) unsigned short wbf[80 * WS];  // bf16 weights (q 0..7, k 8..15, v 16..79); att aliases after P2
    __shared__ float ball[80];
    __shared__ __align__(16) unsigned short vbf[VT * WS];  // bf16 v, [vox][ch], 104 real rows only
    __shared__ __align__(16) float qk[16 * QKS];           // fp32 q rows 0..7, k rows 8..15
    float* const att = (float*)wbf;                        // [w][i][j] = 8*169*4 = 5408 B <= 11520

    const int tid = threadIdx.x;
    const int b   = blockIdx.y;
    const int v0  = blockIdx.x * VT;
    const size_t total = (size_t)512 * NTOT;   // 8*64 rows of x

    // ---- P1: staging, split across waves.
    // Waves 0..3 (tid<224): x -> bf16 transposed LDS. Each thread owns 8 ch x 4 vox,
    // 4 x ds_write_b128 full 16B row segments; quad-group (4vq+r+cg8)%8 uniform
    // 8 lanes/group (wave64-b128 minimum). Global: 8x128B contiguous per load instr. ----
    if (tid < 224) {
        const int vq = tid >> 3, cg8 = tid & 7;
        const int c0 = cg8 * 8, vx = vq * 4;
        float xv[4][8];
#pragma unroll
        for (int i = 0; i < 8; ++i) {
            size_t idx = (size_t)(b * 64 + c0 + i) * NTOT + v0 + vx;
            if (idx > total - 4) idx = total - 4;   // clamp tail (garbage MFMA cols)
            const float4 t = *(const float4*)(x + idx);
            xv[0][i] = t.x; xv[1][i] = t.y; xv[2][i] = t.z; xv[3][i] = t.w;
        }
#pragma unroll
        for (int r = 0; r < 4; ++r) {
            uint4 pk;
            pk.x = pk2(xv[r][0], xv[r][1]);
            pk.y = pk2(xv[r][2], xv[r][3]);
            pk.z = pk2(xv[r][4], xv[r][5]);
            pk.w = pk2(xv[r][6], xv[r][7]);
            *(uint4*)(&xT[(vx + r) * WS + c0]) = pk;
        }
    } else if (tid >= 256) {
        // Waves 4..7: weights -> bf16 LDS, b128 writes (8 ch per item).
        const int wf0 = tid - 256;
#pragma unroll
        for (int it = 0; it < 3; ++it) {
            const int wf = wf0 + (it << 8);
            if (wf < 640) {
                const int r = wf >> 3, cw = (wf & 7) * 8;
                const float* src = (r < 8)  ? (wq + r * 64 + cw)
                                 : (r < 16) ? (wk + (r - 8) * 64 + cw)
                                            : (wv + (r - 16) * 64 + cw);
                const float4 w0 = *(const float4*)src;
                const float4 w1 = *(const float4*)(src + 4);
                uint4 pk;
                pk.x = pk2(w0.x, w0.y); pk.y = pk2(w0.z, w0.w);
                pk.z = pk2(w1.x, w1.y); pk.w = pk2(w1.z, w1.w);
                *(uint4*)(&wbf[r * WS + cw]) = pk;
            }
        }
    }
    if (tid >= 432) {   // 80 bias loads
        const int t2 = tid - 432;
        ball[t2] = (t2 < 8) ? bq[t2] : (t2 < 16) ? bk[t2 - 8] : bv[t2 - 16];
    }
    __syncthreads();

    // ---- P2: projection GEMM via MFMA. 5 m-tiles x 7 n-tiles, K=64 (2 mfma).
    // 35 tiles over 8 waves. A-frag: m=lane&15, k=(lane>>4)*8+j; B-frag: n=lane&15;
    // D: row=(lane>>4)*4+reg, col=lane&15  [m89/m91-verified]. ----
    {
        const int wid  = tid >> 6;
        const int lane = tid & 63;
        const int col  = lane & 15;
        const int g    = lane >> 4;          // k-chunk / row-quad
        for (int t = wid; t < 35; t += 8) {
            const int mt = t / 7, nt = t % 7;
            const shortx8 a0 = *(const shortx8*)(&wbf[(mt * 16 + col) * WS + g * 8]);
            const shortx8 b0 = *(const shortx8*)(&xT [(nt * 16 + col) * WS + g * 8]);
            const shortx8 a1 = *(const shortx8*)(&wbf[(mt * 16 + col) * WS + 32 + g * 8]);
            const shortx8 b1 = *(const shortx8*)(&xT [(nt * 16 + col) * WS + 32 + g * 8]);
            floatx4 acc = {0.f, 0.f, 0.f, 0.f};
            acc = __builtin_amdgcn_mfma_f32_16x16x32_bf16(a0, b0, acc, 0, 0, 0);
            acc = __builtin_amdgcn_mfma_f32_16x16x32_bf16(a1, b1, acc, 0, 0, 0);
            const int row0 = mt * 16 + g * 4;
            const int vox  = nt * 16 + col;
            if (mt == 0) {                    // q/k rows -> qk (fp32, row-major)
                qk[(row0 + 0) * QKS + vox] = acc[0] + ball[row0 + 0];
                qk[(row0 + 1) * QKS + vox] = acc[1] + ball[row0 + 1];
                qk[(row0 + 2) * QKS + vox] = acc[2] + ball[row0 + 2];
                qk[(row0 + 3) * QKS + vox] = acc[3] + ball[row0 + 3];
            } else if (vox < VT) {            // v rows -> bf16, 4 ch = one b64
                const int c0 = row0 - 16;
                uint2 st;
                st.x = pk2(acc[0] + ball[row0 + 0], acc[1] + ball[row0 + 1]);
                st.y = pk2(acc[2] + ball[row0 + 2], acc[3] + ball[row0 + 3]);
                *(uint2*)(&vbf[vox * WS + c0]) = st;
            }
        }
    }
    __syncthreads();

    // ---- P3a: scores[w][i][j] = sum_o q[o][w13+i] * k[o][w13+j].
    // (att aliases wbf — weights are dead from here on.) ----
    for (int f = tid; f < WPB * 169; f += 512) {
        const int w = f / 169, rem = f % 169;
        const int i = rem / 13, j = rem % 13;
        const float* qp = &qk[w * 13 + i];
        const float* kp = &qk[w * 13 + j];
        float s = 0.f;
#pragma unroll
        for (int o = 0; o < 8; ++o)
            s += qp[o * QKS] * kp[(8 + o) * QKS];
        att[f] = s;
    }
    __syncthreads();

    // ---- P3b: softmax over j (one thread per (w,i) row) ----
    if (tid < WPB * WINDOW) {
        float* row = att + tid * 13;
        float m = row[0];
#pragma unroll
        for (int j = 1; j < 13; ++j) m = fmaxf(m, row[j]);
        float s0 = __expf(row[0] - m), s1 = __expf(row[1] - m), s2 = __expf(row[2] - m);
        float s3 = __expf(row[3] - m), s4 = __expf(row[4] - m), s5 = __expf(row[5] - m);
        float s6 = __expf(row[6] - m), s7 = __expf(row[7] - m), s8 = __expf(row[8] - m);
        float s9 = __expf(row[9] - m), sa = __expf(row[10] - m), sb = __expf(row[11] - m);
        float sc = __expf(row[12] - m);
        const float inv = 1.f / (s0+s1+s2+s3+s4+s5+s6+s7+s8+s9+sa+sb+sc);
        row[0]=s0*inv; row[1]=s1*inv; row[2]=s2*inv; row[3]=s3*inv; row[4]=s4*inv;
        row[5]=s5*inv; row[6]=s6*inv; row[7]=s7*inv; row[8]=s8*inv; row[9]=s9*inv;
        row[10]=sa*inv; row[11]=sb*inv; row[12]=sc*inv;
    }
    __syncthreads();

    // ---- P4: out[8cg+r][vx] = sum_j vbf[w13+j][8cg+r] * att[w][i][j].
    // bf16 v: uint4 = 8 channels per read; 16B-group (9*vox+cg)%8 -> uniform
    // 8 lanes/group for consecutive-vx lanes. vx-fast -> stores voxel-contiguous. ----
    for (int f = tid; f < 8 * VT; f += 512) {
        const int cg = f / VT, vx = f % VT;
        const int w = vx / 13, i = vx % 13;
        const float* arow = att + w * 169 + i * 13;
        const unsigned short* vbase = &vbf[(w * 13) * WS + cg * 8];
        float o0=0.f,o1=0.f,o2=0.f,o3=0.f,o4=0.f,o5=0.f,o6=0.f,o7=0.f;
#pragma unroll
        for (int j = 0; j < 13; ++j) {
            const float a = arow[j];
            const uint4 vv = *(const uint4*)(vbase + j * WS);
            o0 += a * bflo(vv.x); o1 += a * bfhi(vv.x);
            o2 += a * bflo(vv.y); o3 += a * bfhi(vv.y);
            o4 += a * bflo(vv.z); o5 += a * bfhi(vv.z);
            o6 += a * bflo(vv.w); o7 += a * bfhi(vv.w);
        }
        float* op = out + (size_t)(b * 64 + cg * 8) * NTOT + v0 + vx;
        op[0]                 = o0;
        op[(size_t)NTOT]      = o1;
        op[(size_t)2 * NTOT]  = o2;
        op[(size_t)3 * NTOT]  = o3;
        op[(size_t)4 * NTOT]  = o4;
        op[(size_t)5 * NTOT]  = o5;
        op[(size_t)6 * NTOT]  = o6;
        op[(size_t)7 * NTOT]  = o7;
    }
}

extern "C" void kernel_launch(void* const* d_in, const int* in_sizes, int n_in,
                              void* d_out, int out_size, void* d_ws, size_t ws_size,
                              hipStream_t stream) {
    const float* x  = (const float*)d_in[0];
    const float* wq = (const float*)d_in[1];
    const float* bq = (const float*)d_in[2];
    const float* wk = (const float*)d_in[3];
    const float* bk = (const float*)d_in[4];
    const float* wv = (const float*)d_in[5];
    const float* bv = (const float*)d_in[6];
    float* out = (float*)d_out;

    dim3 grid(NTOT / VT, 8);   // 512 tiles x 8 batches = 4096 blocks
    dim3 block(512);
    attn_win13_kernel<<<grid, block, 0, stream>>>(x, wq, bq, wk, bk, wv, bv, out);
}